// Round 2
// baseline (22991.110 us; speedup 1.0000x reference)
//
#include <hip/hip_runtime.h>
#include <cstdint>
#include <cstddef>

#define BD 32
#define TD 4096
#define ID 256
#define OD 256

// f32 constants, computed in f64 and rounded (matches np.exp on f32)
#define A_DEND 0.90483741803595957f   // exp(-1/10)
#define A_SYN  0.81873075307798182f   // exp(-1/5)
#define A_MEM  0.95122942450071402f   // exp(-1/20)
#define TWO_PI_F 6.28318530717958647692f
#define BASE_DTH 62.8318530717958647692f  // 2*pi*10
#define INV256 0.00390625f

// ---------------------------------------------------------------------------
// Phase A: vector-ALU GEMM, C-tile = 128 m x (16 o x 7 proj) per 256-thr block.
// kc=16, double-buffered LDS for BOTH x and weights. Thread (tx,ty) owns
// o = o0+tx and m = m0+8*ty..+7, computing all 7 projections of its o.
// Accumulation order (k-ascending fmaf) bit-identical to round-1 kernel.
// ---------------------------------------------------------------------------

// x LDS slot (float4 units): groups of 8 m padded by 1 float4 so the four
// broadcast groups (ty mod 4) land on disjoint bank quads.
__device__ __forceinline__ int xslot(int g, int m) { return g * 144 + m + (m >> 3); }
// w LDS slot: row stride 5 float4 (80 B) -> <=2-way conflict on b128 reads.
__device__ __forceinline__ int wslot(int rp, int g) { return rp * 5 + g; }

__global__ __launch_bounds__(256, 3)
void proj_kernel(const float* __restrict__ x,
                 const float* __restrict__ Ws,
                 const float* __restrict__ Wb,
                 const float* __restrict__ Wa,
                 float* __restrict__ soma_ws,
                 float* __restrict__ u_ws) {
  __shared__ float4 xl[2][576];   // 2 x 9216 B
  __shared__ float4 wl[2][560];   // 2 x 8960 B

  const int tid = threadIdx.x;
  const int tx = tid & 15;        // o_local
  const int ty = tid >> 4;        // m-group (8 rows each)
  const int o0 = blockIdx.x << 4;
  const int m0 = blockIdx.y << 7;
  const int o  = o0 + tx;

  // ---- staging descriptors (advance by 16 floats per chunk) ----
  // x tile: 128 rows x 16 floats = 512 float4; idx = tid and tid+256.
  const int xr = tid >> 2, xg = tid & 3;
  const float* gx0 = x + (size_t)(m0 + xr) * ID + (xg << 2);
  const float* gx1 = gx0 + (size_t)64 * ID;
  const int xs0 = xslot(xg, xr), xs1 = xslot(xg, xr + 64);

  // w tile: 112 rows (p*16+ol) x 16 floats = 448 float4; idx = tid, tid+256(<448).
  auto wrow = [&](int rp) -> const float* {
    int p = rp >> 4, ol = rp & 15;
    const float* base = (p == 0) ? Ws
                       : (p <= 4) ? (Wb + (size_t)(p - 1) * (OD * ID))
                                  : (Wa + (size_t)(p - 5) * (OD * ID));
    return base + (size_t)(o0 + ol) * ID;
  };
  const int wr0 = tid >> 2, wg = tid & 3;
  const float* gw0 = wrow(wr0) + (wg << 2);
  const int ws0 = wslot(wr0, wg);
  const bool w1act = tid < 192;
  const int wr1 = wr0 + 64;
  const float* gw1 = w1act ? (wrow(wr1) + (wg << 2)) : gw0;
  const int ws1 = wslot(wr1, wg);

  float acc[7][8];
  #pragma unroll
  for (int p = 0; p < 7; ++p)
    #pragma unroll
    for (int r = 0; r < 8; ++r) acc[p][r] = 0.f;

  // prologue: stage chunk 0
  float4 rx0 = *(const float4*)gx0;
  float4 rx1 = *(const float4*)gx1;
  float4 rw0 = *(const float4*)gw0;
  float4 rw1 = *(const float4*)gw1;
  xl[0][xs0] = rx0; xl[0][xs1] = rx1;
  wl[0][ws0] = rw0; if (w1act) wl[0][ws1] = rw1;
  __syncthreads();

  const int mbase = ty << 3;
  for (int c = 0; c < 16; ++c) {
    const int cur = c & 1;
    if (c < 15) {  // issue next chunk's global loads early
      const int koff = (c + 1) << 4;
      rx0 = *(const float4*)(gx0 + koff);
      rx1 = *(const float4*)(gx1 + koff);
      rw0 = *(const float4*)(gw0 + koff);
      rw1 = *(const float4*)(gw1 + koff);
    }
    const float4* xb = xl[cur];
    const float4* wb = wl[cur];
    #pragma unroll
    for (int g = 0; g < 4; ++g) {
      float4 xq[8], wq[7];
      #pragma unroll
      for (int r = 0; r < 8; ++r) xq[r] = xb[xslot(g, mbase + r)];
      #pragma unroll
      for (int p = 0; p < 7; ++p) wq[p] = wb[wslot(p * 16 + tx, g)];
      #pragma unroll
      for (int p = 0; p < 7; ++p) {
        #pragma unroll
        for (int r = 0; r < 8; ++r) {
          acc[p][r] = fmaf(xq[r].x, wq[p].x, acc[p][r]);
          acc[p][r] = fmaf(xq[r].y, wq[p].y, acc[p][r]);
          acc[p][r] = fmaf(xq[r].z, wq[p].z, acc[p][r]);
          acc[p][r] = fmaf(xq[r].w, wq[p].w, acc[p][r]);
        }
      }
    }
    if (c < 15) {
      const int nxt = cur ^ 1;
      xl[nxt][xs0] = rx0; xl[nxt][xs1] = rx1;
      wl[nxt][ws0] = rw0; if (w1act) wl[nxt][ws1] = rw1;
      __syncthreads();
    }
  }

  // epilogue — expression order identical to round 1 (bit-exact)
  const size_t ob = (size_t)(m0 + mbase) * OD + o;
  #pragma unroll
  for (int r = 0; r < 8; ++r) {
    float bm = ((fmaxf(acc[1][r], 0.f) + fmaxf(acc[2][r], 0.f)) +
                (fmaxf(acc[3][r], 0.f) + fmaxf(acc[4][r], 0.f))) * 0.25f;
    float am = (fmaxf(acc[5][r], 0.f) + fmaxf(acc[6][r], 0.f)) * 0.5f;
    soma_ws[ob + (size_t)r * OD] = acc[0][r];
    u_ws[ob + (size_t)r * OD]    = bm + am;
  }
}

// ---------------------------------------------------------------------------
// Phase B: sequential LIF + Kuramoto. 32 blocks x 1 wave; lane owns o=4l..4l+3.
// Spike = (v>0) exactly (sigmoid straight-through is bit-exactly 0/1).
// 2-chunk (8-step) prefetch covers ~900-cyc HBM latency.
// ---------------------------------------------------------------------------

#define DPP_ADD(v, ctrl, rm, bm, bc)                                          \
  v += __builtin_bit_cast(float, __builtin_amdgcn_update_dpp(                 \
           0, __builtin_bit_cast(int, v), ctrl, rm, bm, bc));

__device__ __forceinline__ float wave_sum64(float v) {
  DPP_ADD(v, 0x111, 0xf, 0xf, true)    // row_shr:1
  DPP_ADD(v, 0x112, 0xf, 0xf, true)    // row_shr:2
  DPP_ADD(v, 0x114, 0xf, 0xf, true)    // row_shr:4
  DPP_ADD(v, 0x118, 0xf, 0xf, true)    // row_shr:8
  DPP_ADD(v, 0x142, 0xa, 0xf, false)   // row_bcast:15 -> rows 1,3
  DPP_ADD(v, 0x143, 0xc, 0xf, false)   // row_bcast:31 -> rows 2,3
  return __builtin_bit_cast(float, __builtin_amdgcn_readlane(__builtin_bit_cast(int, v), 63));
}

__global__ __launch_bounds__(64, 1)
void dyn_kernel(const float* __restrict__ soma_ws,
                const float* __restrict__ u_ws,
                float* __restrict__ out) {
  #pragma clang fp contract(off)
  const int b = blockIdx.x;
  const int l = threadIdx.x;

  const size_t base4 = ((size_t)b << 18) + l;        // float4 units
  const float4* S = (const float4*)soma_ws + base4;
  const float4* U = (const float4*)u_ws + base4;
  float4* Os = (float4*)out + base4;                 // spikes
  float4* Op = Os + ((size_t)1 << 23);               // phases
  float4* Om = Op + ((size_t)1 << 23);               // membrane

  float dend[4] = {0.f, 0.f, 0.f, 0.f};
  float syn[4]  = {0.f, 0.f, 0.f, 0.f};
  float mem[4]  = {0.f, 0.f, 0.f, 0.f};
  float th[4]   = {0.f, 0.f, 0.f, 0.f};

  const float bD = 1.0f - A_DEND;

  float4 bs[2][4], bu[2][4];
  #pragma unroll
  for (int i = 0; i < 4; ++i) { bs[0][i] = S[(size_t)i * 64];       bu[0][i] = U[(size_t)i * 64]; }
  #pragma unroll
  for (int i = 0; i < 4; ++i) { bs[1][i] = S[(size_t)(4 + i) * 64]; bu[1][i] = U[(size_t)(4 + i) * 64]; }

  for (int t4 = 0; t4 < TD / 4; ++t4) {
    const int sel = t4 & 1;
    float4 cs[4], cu[4];
    #pragma unroll
    for (int i = 0; i < 4; ++i) { cs[i] = bs[sel][i]; cu[i] = bu[sel][i]; }
    if (t4 + 2 < TD / 4) {   // refill freed slot, 2 chunks (8 steps) ahead
      #pragma unroll
      for (int i = 0; i < 4; ++i) {
        bs[sel][i] = S[(size_t)((t4 + 2) * 4 + i) * 64];
        bu[sel][i] = U[(size_t)((t4 + 2) * 4 + i) * 64];
      }
    }
    #pragma unroll
    for (int i = 0; i < 4; ++i) {
      const int t = (t4 << 2) + i;
      const float* sv = &cs[i].x;
      const float* uv = &cu[i].x;
      float spk[4], cc[4], ss[4];
      #pragma unroll
      for (int j = 0; j < 4; ++j) {
        float t1 = A_DEND * dend[j];
        float t2 = bD * uv[j];
        dend[j] = t1 + t2;
        float drive = sv[j] + 0.5f * dend[j];
        syn[j] = (A_SYN * syn[j]) + drive;
        mem[j] = (A_MEM * mem[j]) + syn[j];
        float v = mem[j] - 1.0f;
        // spike_fn forward == exactly 0/1 (Sterbenz: fl(1-sg),fl(0-sg) exact)
        float sp = (v > 0.0f) ? 1.0f : 0.0f;
        mem[j] = mem[j] - sp;
        spk[j] = sp;
        cc[j] = __cosf(th[j]);
        ss[j] = __sinf(th[j]);
      }
      float csum = (cc[0] + cc[1]) + (cc[2] + cc[3]);
      float ssum = (ss[0] + ss[1]) + (ss[2] + ss[3]);
      float cS = wave_sum64(csum);
      float sS = wave_sum64(ssum);
      #pragma unroll
      for (int j = 0; j < 4; ++j) {
        float coup = (sS * cc[j] - cS * ss[j]) * INV256;
        float dth = (BASE_DTH + coup) + spk[j];
        th[j] = th[j] + 0.001f * dth;
        th[j] = (th[j] >= TWO_PI_F) ? (th[j] - TWO_PI_F) : th[j];  // == np.mod (exact)
      }
      float4 so = {spk[0], spk[1], spk[2], spk[3]};
      float4 po = {th[0], th[1], th[2], th[3]};
      float4 mo = {mem[0], mem[1], mem[2], mem[3]};
      Os[(size_t)t * 64] = so;
      Op[(size_t)t * 64] = po;
      Om[(size_t)t * 64] = mo;
    }
  }
}

// ---------------------------------------------------------------------------

extern "C" void kernel_launch(void* const* d_in, const int* in_sizes, int n_in,
                              void* d_out, int out_size, void* d_ws, size_t ws_size,
                              hipStream_t stream) {
  const float* x  = (const float*)d_in[0];
  const float* Ws = (const float*)d_in[1];
  const float* Wb = (const float*)d_in[2];
  const float* Wa = (const float*)d_in[3];

  float* soma_ws = (float*)d_ws;
  float* u_ws    = soma_ws + (size_t)BD * TD * OD;
  float* out     = (float*)d_out;

  dim3 gA(OD / 16, (BD * TD) / 128, 1);   // (16, 1024)
  proj_kernel<<<gA, 256, 0, stream>>>(x, Ws, Wb, Wa, soma_ws, u_ws);
  dyn_kernel<<<BD, 64, 0, stream>>>(soma_ws, u_ws, out);
}

// Round 3
// 18045.990 us; speedup vs baseline: 1.2740x; 1.2740x over previous
//
#include <hip/hip_runtime.h>
#include <cstdint>
#include <cstddef>

#define BD 32
#define TD 4096
#define ID 256
#define OD 256

// f32 constants, computed in f64 and rounded (matches np.exp on f32)
#define A_DEND 0.90483741803595957f   // exp(-1/10)
#define A_SYN  0.81873075307798182f   // exp(-1/5)
#define A_MEM  0.95122942450071402f   // exp(-1/20)
#define TWO_PI_F 6.28318530717958647692f
#define BASE_DTH 62.8318530717958647692f  // 2*pi*10
#define INV256 0.00390625f

// ---------------------------------------------------------------------------
// Phase A: vector-ALU GEMM. Block = 256 thr, C-tile = 64 m x (16 o x 7 proj).
// kc=16 double-buffered LDS for x AND weights. Thread (tx,ty) owns o=o0+tx,
// m = m0+4*ty..+3, all 7 projections. Live set ~80 VGPR; waves_per_eu pinned
// to (4,4) so the allocator cannot chase 6 waves/EU and spill (the R2 bug:
// VGPR budget 84 -> 50-reg spill -> 103 GB of scratch traffic).
// Accumulation order (k-ascending fmaf, xyzw) bit-identical to round 1.
// ---------------------------------------------------------------------------

__global__ __launch_bounds__(256) __attribute__((amdgpu_waves_per_eu(4, 4)))
void proj_kernel(const float* __restrict__ x,
                 const float* __restrict__ Ws,
                 const float* __restrict__ Wb,
                 const float* __restrict__ Wa,
                 float* __restrict__ soma_ws,
                 float* __restrict__ u_ws) {
  // stride-5 float4 rows: row r, k-quad q at slot r*5+q  (<=2-way banks = free)
  __shared__ float4 xl[2][320];   // 64 rows
  __shared__ float4 wl[2][560];   // 112 rows (7p x 16o)

  const int tid = threadIdx.x;
  const int tx = tid & 15;        // o_local
  const int ty = tid >> 4;        // m-group (4 rows)
  const int o0 = blockIdx.x << 4;
  const int m0 = blockIdx.y << 6;
  const int o  = o0 + tx;

  // x staging: thread -> (row=tid>>2, kq=tid&3), one float4/chunk
  const int xr = tid >> 2, kq = tid & 3;
  const float* gx = x + (size_t)(m0 + xr) * ID + (kq << 2);
  const int xs = xr * 5 + kq;

  // w staging: rows rp = p*16+ol; thread covers rp0=tid>>2, rp1=64+(tid>>2) (tid<192)
  auto wrowp = [&](int rp) -> const float* {
    int p = rp >> 4, ol = rp & 15;
    const float* base = (p == 0) ? Ws
                       : (p <= 4) ? (Wb + (size_t)(p - 1) * (OD * ID))
                                  : (Wa + (size_t)(p - 5) * (OD * ID));
    return base + (size_t)(o0 + ol) * ID;
  };
  const int wr0 = tid >> 2;
  const float* gw0 = wrowp(wr0) + (kq << 2);
  const int wsl0 = wr0 * 5 + kq;
  const bool act1 = tid < 192;
  const int wr1 = 64 + (tid >> 2);
  const float* gw1 = act1 ? (wrowp(wr1) + (kq << 2)) : gw0;
  const int wsl1 = wr1 * 5 + kq;

  float acc[7][4];
  #pragma unroll
  for (int p = 0; p < 7; ++p)
    #pragma unroll
    for (int r = 0; r < 4; ++r) acc[p][r] = 0.f;

  // prologue: stage chunk 0
  float4 rx  = *(const float4*)gx;
  float4 rw0 = *(const float4*)gw0;
  float4 rw1 = *(const float4*)gw1;
  xl[0][xs] = rx; wl[0][wsl0] = rw0; if (act1) wl[0][wsl1] = rw1;
  __syncthreads();

  for (int c = 0; c < 16; ++c) {
    const int cur = c & 1;
    if (c < 15) {
      const int koff = (c + 1) << 4;
      rx  = *(const float4*)(gx + koff);
      rw0 = *(const float4*)(gw0 + koff);
      rw1 = *(const float4*)(gw1 + koff);
    }
    const float4* xb = xl[cur];
    const float4* wb = wl[cur];
    #pragma unroll
    for (int k4 = 0; k4 < 4; ++k4) {
      float4 xq[4];
      #pragma unroll
      for (int r = 0; r < 4; ++r) xq[r] = xb[(ty * 4 + r) * 5 + k4];
      #pragma unroll
      for (int p = 0; p < 7; ++p) {
        float4 wq = wb[(p * 16 + tx) * 5 + k4];
        #pragma unroll
        for (int r = 0; r < 4; ++r) {
          acc[p][r] = fmaf(xq[r].x, wq.x, acc[p][r]);
          acc[p][r] = fmaf(xq[r].y, wq.y, acc[p][r]);
          acc[p][r] = fmaf(xq[r].z, wq.z, acc[p][r]);
          acc[p][r] = fmaf(xq[r].w, wq.w, acc[p][r]);
        }
      }
    }
    if (c < 15) {
      const int nxt = cur ^ 1;
      xl[nxt][xs] = rx; wl[nxt][wsl0] = rw0; if (act1) wl[nxt][wsl1] = rw1;
      __syncthreads();
    }
  }

  // epilogue — expression order identical to round 1 (bit-exact)
  const size_t ob = (size_t)(m0 + ty * 4) * OD + o;
  #pragma unroll
  for (int r = 0; r < 4; ++r) {
    float bm = ((fmaxf(acc[1][r], 0.f) + fmaxf(acc[2][r], 0.f)) +
                (fmaxf(acc[3][r], 0.f) + fmaxf(acc[4][r], 0.f))) * 0.25f;
    float am = (fmaxf(acc[5][r], 0.f) + fmaxf(acc[6][r], 0.f)) * 0.5f;
    soma_ws[ob + (size_t)r * OD] = acc[0][r];
    u_ws[ob + (size_t)r * OD]    = bm + am;
  }
}

// ---------------------------------------------------------------------------
// Phase B1: LIF — per-neuron independent, so run at full parallelism:
// 128 blocks x 64 lanes = 8192 lanes, one neuron each, serial over T.
// Writes spikes (out+0) and membrane (out + 2*B*T*O). Bit-identical math.
// ---------------------------------------------------------------------------

__global__ __launch_bounds__(64)
void lif_kernel(const float* __restrict__ soma_ws,
                const float* __restrict__ u_ws,
                float* __restrict__ out) {
  #pragma clang fp contract(off)
  const int o = (blockIdx.x << 6) + threadIdx.x;   // grid.x = 4
  const int b = blockIdx.y;                        // 32
  const size_t base = (size_t)b * TD * OD + o;
  const float* S = soma_ws + base;
  const float* U = u_ws + base;
  float* Osp = out + base;                          // spikes
  float* Omm = out + base + ((size_t)2 * BD * TD * OD);  // membrane

  float dend = 0.f, syn = 0.f, mem = 0.f;
  const float bD = 1.0f - A_DEND;

  float ps[2][4], pu[2][4];
  #pragma unroll
  for (int i = 0; i < 4; ++i) { ps[0][i] = S[(size_t)i * OD];       pu[0][i] = U[(size_t)i * OD]; }
  #pragma unroll
  for (int i = 0; i < 4; ++i) { ps[1][i] = S[(size_t)(4 + i) * OD]; pu[1][i] = U[(size_t)(4 + i) * OD]; }

  for (int t4 = 0; t4 < TD / 4; ++t4) {
    const int sel = t4 & 1;
    float cs[4], cu[4];
    #pragma unroll
    for (int i = 0; i < 4; ++i) { cs[i] = ps[sel][i]; cu[i] = pu[sel][i]; }
    if (t4 + 2 < TD / 4) {
      #pragma unroll
      for (int i = 0; i < 4; ++i) {
        ps[sel][i] = S[(size_t)((t4 + 2) * 4 + i) * OD];
        pu[sel][i] = U[(size_t)((t4 + 2) * 4 + i) * OD];
      }
    }
    #pragma unroll
    for (int i = 0; i < 4; ++i) {
      const int t = (t4 << 2) + i;
      float t1 = A_DEND * dend;
      float t2 = bD * cu[i];
      dend = t1 + t2;
      float drive = cs[i] + 0.5f * dend;
      syn = (A_SYN * syn) + drive;
      mem = (A_MEM * mem) + syn;
      float v = mem - 1.0f;
      // spike_fn forward == exactly 0/1 (Sterbenz: fl(1-sg), fl(0-sg) exact)
      float sp = (v > 0.0f) ? 1.0f : 0.0f;
      mem = mem - sp;
      Osp[(size_t)t * OD] = sp;
      Omm[(size_t)t * OD] = mem;
    }
  }
}

// ---------------------------------------------------------------------------
// Phase B2: Kuramoto — serial over T, coupled across o within b.
// 32 blocks x 1 wave, lane owns theta[4l..4l+3]; reads spikes from out.
// DPP wave64 sums for mean cos/sin. Arithmetic sequence identical to R2.
// ---------------------------------------------------------------------------

#define DPP_ADD(v, ctrl, rm, bm, bc)                                          \
  v += __builtin_bit_cast(float, __builtin_amdgcn_update_dpp(                 \
           0, __builtin_bit_cast(int, v), ctrl, rm, bm, bc));

__device__ __forceinline__ float wave_sum64(float v) {
  DPP_ADD(v, 0x111, 0xf, 0xf, true)    // row_shr:1
  DPP_ADD(v, 0x112, 0xf, 0xf, true)    // row_shr:2
  DPP_ADD(v, 0x114, 0xf, 0xf, true)    // row_shr:4
  DPP_ADD(v, 0x118, 0xf, 0xf, true)    // row_shr:8
  DPP_ADD(v, 0x142, 0xa, 0xf, false)   // row_bcast:15 -> rows 1,3
  DPP_ADD(v, 0x143, 0xc, 0xf, false)   // row_bcast:31 -> rows 2,3
  return __builtin_bit_cast(float, __builtin_amdgcn_readlane(__builtin_bit_cast(int, v), 63));
}

__global__ __launch_bounds__(64)
void kur_kernel(float* __restrict__ out) {
  #pragma clang fp contract(off)
  const int b = blockIdx.x;
  const int l = threadIdx.x;

  const size_t base4 = ((size_t)b << 18) + l;        // float4 units
  const float4* Sp = (const float4*)out + base4;     // spikes (written by lif)
  float4* Op = (float4*)out + base4 + ((size_t)BD * TD * OD / 4);  // phases

  float th[4] = {0.f, 0.f, 0.f, 0.f};

  float4 bs[2][4];
  #pragma unroll
  for (int i = 0; i < 4; ++i) bs[0][i] = Sp[(size_t)i * 64];
  #pragma unroll
  for (int i = 0; i < 4; ++i) bs[1][i] = Sp[(size_t)(4 + i) * 64];

  for (int t4 = 0; t4 < TD / 4; ++t4) {
    const int sel = t4 & 1;
    float4 cspk[4];
    #pragma unroll
    for (int i = 0; i < 4; ++i) cspk[i] = bs[sel][i];
    if (t4 + 2 < TD / 4) {
      #pragma unroll
      for (int i = 0; i < 4; ++i) bs[sel][i] = Sp[(size_t)((t4 + 2) * 4 + i) * 64];
    }
    #pragma unroll
    for (int i = 0; i < 4; ++i) {
      const int t = (t4 << 2) + i;
      const float* spk = &cspk[i].x;
      float cc[4], ss[4];
      #pragma unroll
      for (int j = 0; j < 4; ++j) {
        cc[j] = __cosf(th[j]);
        ss[j] = __sinf(th[j]);
      }
      float csum = (cc[0] + cc[1]) + (cc[2] + cc[3]);
      float ssum = (ss[0] + ss[1]) + (ss[2] + ss[3]);
      float cS = wave_sum64(csum);
      float sS = wave_sum64(ssum);
      #pragma unroll
      for (int j = 0; j < 4; ++j) {
        // K*r*sin(psi - th) == s_mean*cos(th) - c_mean*sin(th)
        float coup = (sS * cc[j] - cS * ss[j]) * INV256;
        float dth = (BASE_DTH + coup) + spk[j];
        th[j] = th[j] + 0.001f * dth;
        th[j] = (th[j] >= TWO_PI_F) ? (th[j] - TWO_PI_F) : th[j];  // == np.mod
      }
      float4 po = {th[0], th[1], th[2], th[3]};
      Op[(size_t)t * 64] = po;
    }
  }
}

// ---------------------------------------------------------------------------

extern "C" void kernel_launch(void* const* d_in, const int* in_sizes, int n_in,
                              void* d_out, int out_size, void* d_ws, size_t ws_size,
                              hipStream_t stream) {
  const float* x  = (const float*)d_in[0];
  const float* Ws = (const float*)d_in[1];
  const float* Wb = (const float*)d_in[2];
  const float* Wa = (const float*)d_in[3];

  float* soma_ws = (float*)d_ws;
  float* u_ws    = soma_ws + (size_t)BD * TD * OD;
  float* out     = (float*)d_out;

  dim3 gA(OD / 16, (BD * TD) / 64, 1);   // (16, 2048)
  proj_kernel<<<gA, 256, 0, stream>>>(x, Ws, Wb, Wa, soma_ws, u_ws);
  lif_kernel<<<dim3(OD / 64, BD, 1), 64, 0, stream>>>(soma_ws, u_ws, out);
  kur_kernel<<<BD, 64, 0, stream>>>(out);
}